// Round 15
// baseline (179.508 us; speedup 1.0000x reference)
//
#include <hip/hip_runtime.h>
#include <cstdint>
#include <cstddef>

// ---------------- problem constants ----------------
#define TSTEPS 192
#define BATCH  4096
#define FRAW   20
#define FCONV  22
#define FCNN   11
#define HID    40
#define NOUT   21
#define ROWSPB 16
#define NTH    1024             // 16 waves: 8x1-tile + 6x2-tile gate waves + 2 head
#define NBLK   (BATCH/ROWSPB)   // 256 blocks = 1 block/CU

#define FEAT_OFF 4096           // ws: feat (fp16) at byte 4096

typedef _Float16 half8 __attribute__((ext_vector_type(8)));
typedef float    f32x4 __attribute__((ext_vector_type(4)));
#define MFMA16(a,b,c) __builtin_amdgcn_mfma_f32_16x16x32_f16(a,b,c,0,0,0)

// LDS-only workgroup barrier (no vmcnt drain: head waves keep global ops in flight)
#define WGBAR() do{ \
    __builtin_amdgcn_sched_barrier(0); \
    asm volatile("s_waitcnt lgkmcnt(0)" ::: "memory"); \
    __builtin_amdgcn_s_barrier(); \
    __builtin_amdgcn_sched_barrier(0); \
}while(0)

// fast reciprocal (v_rcp_f32, ~1 ULP) — avoids precise-div expansion
__device__ __forceinline__ float rcp_(float x){ return __builtin_amdgcn_rcpf(x); }
__device__ __forceinline__ float sigm_(float x){ return rcp_(1.f + __expf(-x)); }
__device__ __forceinline__ float tanh_(float x){ return fmaf(-2.f, rcp_(__expf(2.f*x) + 1.f), 1.f); }
__device__ __forceinline__ float softplus_(float x){
    float t = __expf(-fabsf(x));
    return fmaxf(x,0.f) + 0.6931471805599453f*__log2f(1.f+t);
}

// fragment-layout offset (halves) of logical k, batch-row mr:
// [chunk=k>>5][q=(k>>3)&3][mr][i=k&7]; chunk stride 512, q stride 128
__device__ __forceinline__ int offk(int k, int mr){
    return ((k>>5)*4 + ((k>>3)&3))*128 + mr*8 + (k&7);
}

// -------- kernel 1: FUSED stats + conv/BN/ELU/pool -> fp16 feat -------------
__global__ __launch_bounds__(1024)
void statfeat_kernel(const float* __restrict__ x_enc, const float* __restrict__ y_enc,
                     const float* __restrict__ conv_w, const float* __restrict__ conv_b,
                     const float* __restrict__ bn_w, const float* __restrict__ bn_b,
                     _Float16* __restrict__ feat)
{
    const int t = blockIdx.x;
    const float w0=conv_w[0], w1=conv_w[1], w2=conv_w[2], cb=conv_b[0];
    const float* src = (t < 96) ? (x_enc + (size_t)t*21) : (y_enc + (size_t)(t-96)*21);

    float xv[4][FRAW];
    float s=0.f, ss=0.f;
    #pragma unroll
    for (int rr=0; rr<4; ++rr){
        const int row = threadIdx.x + 1024*rr;
        const float* xr = src + (size_t)row*2016;    // 96*21
        #pragma unroll
        for (int f=0; f<FRAW; ++f) xv[rr][f] = xr[f];
        #pragma unroll
        for (int i=0; i<FCONV; ++i){
            float y = fmaf(w0, xv[rr][(i+18)%20], fmaf(w1, xv[rr][(i+19)%20], fmaf(w2, xv[rr][i%20], cb)));
            s += y; ss = fmaf(y, y, ss);
        }
    }
    #pragma unroll
    for (int o=32; o>0; o>>=1){ s += __shfl_down(s,o); ss += __shfl_down(ss,o); }
    __shared__ float rs[16], rq[16], ab[2];
    const int wid = threadIdx.x >> 6, lid = threadIdx.x & 63;
    if (lid == 0){ rs[wid]=s; rq[wid]=ss; }
    __syncthreads();
    if (threadIdx.x == 0){
        float S=0.f, Q=0.f;
        #pragma unroll
        for (int i=0;i<16;++i){ S+=rs[i]; Q+=rq[i]; }
        const float N = (float)BATCH*(float)FCONV;
        float mu  = S/N;
        float var = Q/N - mu*mu;
        float A   = rsqrtf(var + 1e-5f) * bn_w[0];
        ab[0]=A; ab[1]=bn_b[0] - mu*A;
    }
    __syncthreads();
    const float A = ab[0], Bc = ab[1];

    #pragma unroll
    for (int rr=0; rr<4; ++rr){
        const int row = threadIdx.x + 1024*rr;
        float yv[FCONV];
        #pragma unroll
        for (int i=0; i<FCONV; ++i){
            float y = fmaf(w0, xv[rr][(i+18)%20], fmaf(w1, xv[rr][(i+19)%20], fmaf(w2, xv[rr][i%20], cb)));
            y = fmaf(y, A, Bc);
            yv[i] = (y > 0.f) ? y : (__expf(y) - 1.f);   // ELU
        }
        _Float16* fo = feat + ((size_t)t*BATCH + row)*FCNN;
        #pragma unroll
        for (int i=0; i<FCNN; ++i){
            float m = (i==0) ? fmaxf(yv[0], yv[1])
                             : fmaxf(yv[2*i-1], fmaxf(yv[2*i], yv[2*i+1]));
            fo[i] = (_Float16)m;
        }
    }
}

// -------- kernel 2: unified-buffer pipelined MFMA LSTM, 16 waves ------------
// Same dataflow/races/numerics as R14; ONLY the wave decomposition changes:
//   wv 0-3 : L0, 1 tile (tiles 0-3)        wv 4-7 : L1, 1 tile (tiles 0-3)
//   wv 8-10: L0, 2 tiles (4,5 / 6,7 / 8,9) wv 11-13: L1, 2 tiles (same)
//   wv 14-15: heads + feat staging
// -> 4 waves/SIMD (was 3) and shorter per-wave serial chains for latency
// hiding; total issued work per CU unchanged.
// V (mod-3), K=96, fp16: k 0..10 feat | 11..50 h0 | 51..55 ZERO | 56..95 h1.
// W hi/lo split in registers (REQUIRED per R13 failure); x/h fp16 (proven).
__global__ __launch_bounds__(NTH, 4)
void lstm_kernel(const _Float16* __restrict__ feat,
                 const float* __restrict__ w_ih0, const float* __restrict__ w_hh0, const float* __restrict__ b0,
                 const float* __restrict__ w_ih1, const float* __restrict__ w_hh1, const float* __restrict__ b1,
                 const float* __restrict__ w_gamma, const float* __restrict__ b_gamma,
                 const float* __restrict__ w_eta,   const float* __restrict__ b_eta,
                 float* __restrict__ out)
{
    __shared__ __align__(16) _Float16 V[3*1536];

    const int tid  = threadIdx.x;
    const int l    = tid & 63;
    const int wv   = tid >> 6;
    const int q    = l >> 4;
    const int mr   = l & 15;
    const int row0 = blockIdx.x * ROWSPB;

    // role decomposition (wave-uniform)
    int role, t0, ntl;
    if      (wv < 4){  role=0; t0=wv;           ntl=1; }
    else if (wv < 8){  role=1; t0=wv-4;         ntl=1; }
    else if (wv < 11){ role=0; t0=4+2*(wv-8);   ntl=2; }
    else if (wv < 14){ role=1; t0=4+2*(wv-11);  ntl=2; }
    else            {  role=2; t0=0;            ntl=0; }
    const bool isL0 = (role==0), isL1 = (role==1);
    const bool two  = (ntl==2);

    // ---- zero LDS (k51-55 / k91-95 pads must stay zero forever) ----
    { uint32_t* z=(uint32_t*)V; for(int i=tid;i<2304;i+=NTH) z[i]=0u; }

    // =================== per-role setup ===================
    half8 a0h[2][2], a0l[2][2];
    half8 a1h[2][3], a1l[2][3];
    half8 ahd[3];
    f32x4 bias0[2]={{0,0,0,0},{0,0,0,0}}, bias1[2]={{0,0,0,0},{0,0,0,0}};
    f32x4 biash={0,0,0,0};
    int woH0[2]={0,0}, woH1[2]={0,0};
    int fW0=0, fW1=0; bool fV0=false, fV1=false;
    const _Float16* fG0 = feat; const _Float16* fG1 = feat;

    if (isL0){
        #pragma unroll
        for (int g=0; g<2; ++g){
            if (g < ntl){
                const int T  = t0 + g;
                const int uA = 4*T + (mr >> 2);
                const int RA = (mr & 3)*40 + uA;       // torch row: gate-major
                #pragma unroll
                for (int cc=0; cc<2; ++cc){
                    #pragma unroll
                    for (int ii=0; ii<8; ++ii){
                        int k = 32*cc + 8*q + ii;
                        float v = (k<11) ? w_ih0[RA*11+k] : ((k<51) ? w_hh0[RA*40+k-11] : 0.f);
                        _Float16 h = (_Float16)v;
                        a0h[g][cc][ii]=h; a0l[g][cc][ii]=(_Float16)(v-(float)h);
                    }
                }
                const int u = 4*T + q;
                bias0[g][0]=b0[u]; bias0[g][1]=b0[40+u]; bias0[g][2]=b0[80+u]; bias0[g][3]=b0[120+u];
                woH0[g] = offk(11+u, mr);
            }
        }
    } else if (isL1){
        #pragma unroll
        for (int g=0; g<2; ++g){
            if (g < ntl){
                const int T  = t0 + g;
                const int uA = 4*T + (mr >> 2);
                const int RA = (mr & 3)*40 + uA;
                #pragma unroll
                for (int cc=0; cc<3; ++cc){
                    #pragma unroll
                    for (int ii=0; ii<8; ++ii){
                        int k = 32*cc + 8*q + ii;
                        float v = 0.f;
                        if (k>=11 && k<51)      v = w_ih1[RA*40 + (k-11)];
                        else if (k>=56)         v = w_hh1[RA*40 + (k-56)];
                        _Float16 h = (_Float16)v;
                        a1h[g][cc][ii]=h; a1l[g][cc][ii]=(_Float16)(v-(float)h);
                    }
                }
                const int u = 4*T + q;
                bias1[g][0]=b1[u]; bias1[g][1]=b1[40+u]; bias1[g][2]=b1[80+u]; bias1[g][3]=b1[120+u];
                woH1[g] = offk(56+u, mr);
            }
        }
    } else {
        const int hw = wv - 14;
        const int jo = 16*hw + mr;
        #pragma unroll
        for (int cc=0; cc<3; ++cc){
            #pragma unroll
            for (int ii=0; ii<8; ++ii){
                int k = 32*cc + 8*q + ii;
                float v = 0.f;
                if (jo < NOUT){
                    if (k>=11 && k<51) v = (jo==0) ? w_gamma[2*(k-11)]   : w_eta[(jo-1)*80 + 2*(k-11)];
                    else if (k>=56)    v = (jo==0) ? w_gamma[2*(k-56)+1] : w_eta[(jo-1)*80 + 2*(k-56)+1];
                }
                ahd[cc][ii] = (_Float16)v;
            }
        }
        #pragma unroll
        for (int e=0; e<4; ++e){
            int j2 = 16*hw + 4*q + e;
            biash[e] = (j2 < NOUT) ? ((j2==0) ? b_gamma[0] : b_eta[j2-1]) : 0.f;
        }
        const int hl = tid - 896;                      // 0..127
        int i0 = hl, i1 = hl + 128;
        fV0 = (i0 < ROWSPB*FCNN); fV1 = (i1 < ROWSPB*FCNN);
        { int r = i0/FCNN, f = i0 - FCNN*r; r &= 15; fW0 = offk(f, r);
          fG0 = feat + (size_t)(row0 + r)*FCNN + f; }
        { int ix = fV1 ? i1 : 0;
          int r = ix/FCNN, f = ix - FCNN*(ix/FCNN); r &= 15; fW1 = offk(f, r);
          fG1 = feat + (size_t)(row0 + r)*FCNN + f; }
    }

    __syncthreads();    // zero-init visible before feat(0) staging
    _Float16 fA0=(_Float16)0.f, fA1=(_Float16)0.f, fB0=(_Float16)0.f, fB1=(_Float16)0.f;
    if (role == 2){
        if (fV0) V[fW0] = fG0[0];                      // feat(0) -> V[0]
        if (fV1) V[fW1] = fG1[0];
        const size_t fs = (size_t)BATCH*FCNN;          // preload feat(1)
        if (fV0) fB0 = fG0[fs];
        if (fV1) fB1 = fG1[fs];
    }
    __syncthreads();

    float c0[2]={0.f,0.f}, c1[2]={0.f,0.f};
    const size_t featStep = (size_t)BATCH*FCNN;
    const _Float16* Vr = V + l*8;                      // hoisted read base

    if (isL0){
        _Float16* wpa = V + woH0[0];
        _Float16* wpb = V + woH0[1];
        #define L0T(G,WP,C,CN) do{ \
            f32x4 acc = bias0[G]; \
            acc = MFMA16(a0h[G][0], x0, acc); \
            acc = MFMA16(a0l[G][0], x0, acc); \
            acc = MFMA16(a0h[G][1], x1, acc); \
            acc = MFMA16(a0l[G][1], x1, acc); \
            float ig=sigm_(acc[0]), fg=sigm_(acc[1]), gv=tanh_(acc[2]), og=sigm_(acc[3]); \
            c0[G] = fmaf(fg, c0[G], ig*gv); \
            WP[(CN)*1536] = (_Float16)(og * tanh_(c0[G])); \
        }while(0)
        #define L0B(C,CN) do{ \
            half8 x0 = *(const half8*)(Vr + (C)*1536); \
            half8 x1 = *(const half8*)(Vr + (C)*1536 + 512); \
            L0T(0,wpa,C,CN); \
            if (two) L0T(1,wpb,C,CN); \
        }while(0)
        L0B(0,1); WGBAR();      // i = 0
        L0B(1,2); WGBAR();      // i = 1
        for (int m=0; m<32; ++m){
            #pragma unroll
            for (int k=0; k<6; ++k){
                const int i = 2 + 6*m + k;
                if (i < TSTEPS) L0B((k+2)%3, k%3);
                WGBAR();
            }
        }
        #undef L0B
        #undef L0T
    } else if (isL1){
        _Float16* wpa = V + woH1[0];
        _Float16* wpb = V + woH1[1];
        #define L1T(G,WP,C,CN) do{ \
            f32x4 cA = bias1[G]; \
            cA = MFMA16(a1h[G][0], y0, cA); cA = MFMA16(a1l[G][0], y0, cA); \
            cA = MFMA16(a1h[G][1], y1, cA); cA = MFMA16(a1l[G][1], y1, cA); \
            f32x4 cB = {0.f,0.f,0.f,0.f}; \
            cB = MFMA16(a1h[G][2], y2, cB); cB = MFMA16(a1l[G][2], y2, cB); \
            f32x4 acc = cA + cB; \
            float ig=sigm_(acc[0]), fg=sigm_(acc[1]), gv=tanh_(acc[2]), og=sigm_(acc[3]); \
            c1[G] = fmaf(fg, c1[G], ig*gv); \
            WP[(CN)*1536] = (_Float16)(og * tanh_(c1[G])); \
        }while(0)
        #define L1B(C,CN) do{ \
            half8 y0 = *(const half8*)(Vr + (C)*1536); \
            half8 y1 = *(const half8*)(Vr + (C)*1536 + 512); \
            half8 y2 = *(const half8*)(Vr + (C)*1536 + 1024); \
            L1T(0,wpa,C,CN); \
            if (two) L1T(1,wpb,C,CN); \
        }while(0)
        WGBAR();                // i = 0 (L1 idle)
        L1B(1,2); WGBAR();      // i = 1
        for (int m=0; m<32; ++m){
            #pragma unroll
            for (int k=0; k<6; ++k){
                const int i = 2 + 6*m + k;
                if (i <= TSTEPS) L1B((k+2)%3, k%3);
                WGBAR();
            }
        }
        #undef L1B
        #undef L1T
    } else {
        _Float16* fp0 = V + fW0;
        _Float16* fp1 = V + fW1;
        const int hw  = wv - 14;
        const int jb  = 16*hw + 4*q;
        float* outB = out + (size_t)(row0 + mr)*NOUT + jb;
        #define HFEAT(CN,PAR,I) do{ \
            if ((I) < TSTEPS-1){ \
                _Float16 v0 = (PAR) ? fA0 : fB0; \
                _Float16 v1 = (PAR) ? fA1 : fB1; \
                if (fV0) fp0[(CN)*1536] = v0; \
                if (fV1) fp1[(CN)*1536] = v1; \
            } \
            if ((I)+2 < TSTEPS){ \
                size_t o = (size_t)((I)+2)*featStep; \
                if (PAR){ if(fV0) fB0=fG0[o]; if(fV1) fB1=fG1[o]; } \
                else    { if(fV0) fA0=fG0[o]; if(fV1) fA1=fG1[o]; } \
            } \
        }while(0)
        #define HOUT(C,CP,I) do{ \
            half8 z0 = *(const half8*)(Vr + (CP)*1536); \
            half8 z1 = *(const half8*)(Vr + ((q<3)?(CP):(C))*1536 + 512); \
            half8 z2 = *(const half8*)(Vr + (C)*1536 + 1024); \
            f32x4 H = biash; \
            H = MFMA16(ahd[0], z0, H); \
            H = MFMA16(ahd[1], z1, H); \
            H = MFMA16(ahd[2], z2, H); \
            float* op = outB + (size_t)((I)-2)*(BATCH*NOUT); \
            if (hw==0 || q==0){ \
                op[0]=softplus_(H[0]); op[1]=softplus_(H[1]); \
                op[2]=softplus_(H[2]); op[3]=softplus_(H[3]); \
            } else if (q==1){ \
                op[0]=softplus_(H[0]); \
            } \
        }while(0)
        HFEAT(1,0,0); WGBAR();      // i = 0
        HFEAT(2,1,1); WGBAR();      // i = 1
        for (int m=0; m<32; ++m){
            #pragma unroll
            for (int k=0; k<6; ++k){
                const int i = 2 + 6*m + k;
                HFEAT(k%3, k%2, i);
                HOUT((k+2)%3, (k+1)%3, i);
                WGBAR();
            }
        }
        #undef HFEAT
        #undef HOUT
    }
}

// ---------------------------------------------------------------------------
extern "C" void kernel_launch(void* const* d_in, const int* in_sizes, int n_in,
                              void* d_out, int out_size, void* d_ws, size_t ws_size,
                              hipStream_t stream)
{
    (void)in_sizes; (void)n_in; (void)out_size; (void)ws_size;
    const float* x_enc   = (const float*)d_in[0];
    const float* y_enc   = (const float*)d_in[3];
    const float* conv_w  = (const float*)d_in[5];
    const float* conv_b  = (const float*)d_in[6];
    const float* bn_w    = (const float*)d_in[7];
    const float* bn_b    = (const float*)d_in[8];
    const float* w_ih0   = (const float*)d_in[9];
    const float* w_hh0   = (const float*)d_in[10];
    const float* b0      = (const float*)d_in[11];
    const float* w_ih1   = (const float*)d_in[12];
    const float* w_hh1   = (const float*)d_in[13];
    const float* b1      = (const float*)d_in[14];
    const float* w_gamma = (const float*)d_in[15];
    const float* b_gamma = (const float*)d_in[16];
    const float* w_eta   = (const float*)d_in[17];
    const float* b_eta   = (const float*)d_in[18];

    float*     out   = (float*)d_out;
    _Float16*  feat  = (_Float16*)((char*)d_ws + FEAT_OFF);

    statfeat_kernel<<<TSTEPS, 1024, 0, stream>>>(x_enc, y_enc, conv_w, conv_b, bn_w, bn_b, feat);
    lstm_kernel<<<NBLK, NTH, 0, stream>>>(feat,
        w_ih0, w_hh0, b0, w_ih1, w_hh1, b1, w_gamma, b_gamma, w_eta, b_eta, out);
}

// Round 16
// 165.070 us; speedup vs baseline: 1.0875x; 1.0875x over previous
//
#include <hip/hip_runtime.h>
#include <cstdint>
#include <cstddef>

// ---------------- problem constants ----------------
#define TSTEPS 192
#define BATCH  4096
#define FRAW   20
#define FCONV  22
#define FCNN   11
#define HID    40
#define NOUT   21
#define ROWSPB 16
#define NTH    1024             // 16 waves, 5 gate-tiles per SIMD (balanced)
#define NBLK   (BATCH/ROWSPB)   // 256 blocks = 1 block/CU

#define FEAT_OFF 4096           // ws: feat (fp16) at byte 4096

typedef _Float16 half8 __attribute__((ext_vector_type(8)));
typedef float    f32x4 __attribute__((ext_vector_type(4)));
#define MFMA16(a,b,c) __builtin_amdgcn_mfma_f32_16x16x32_f16(a,b,c,0,0,0)

// LDS-only workgroup barrier (no vmcnt drain: head/feat waves keep global ops in flight)
#define WGBAR() do{ \
    __builtin_amdgcn_sched_barrier(0); \
    asm volatile("s_waitcnt lgkmcnt(0)" ::: "memory"); \
    __builtin_amdgcn_s_barrier(); \
    __builtin_amdgcn_sched_barrier(0); \
}while(0)

// fast reciprocal (v_rcp_f32, ~1 ULP) — avoids precise-div expansion
__device__ __forceinline__ float rcp_(float x){ return __builtin_amdgcn_rcpf(x); }
__device__ __forceinline__ float sigm_(float x){ return rcp_(1.f + __expf(-x)); }
__device__ __forceinline__ float tanh_(float x){ return fmaf(-2.f, rcp_(__expf(2.f*x) + 1.f), 1.f); }
__device__ __forceinline__ float softplus_(float x){
    float t = __expf(-fabsf(x));
    return fmaxf(x,0.f) + 0.6931471805599453f*__log2f(1.f+t);
}

// fragment-layout offset (halves) of logical k, batch-row mr:
// [chunk=k>>5][q=(k>>3)&3][mr][i=k&7]; chunk stride 512, q stride 128
__device__ __forceinline__ int offk(int k, int mr){
    return ((k>>5)*4 + ((k>>3)&3))*128 + mr*8 + (k&7);
}

// -------- kernel 1: FUSED stats + conv/BN/ELU/pool -> fp16 feat -------------
__global__ __launch_bounds__(1024)
void statfeat_kernel(const float* __restrict__ x_enc, const float* __restrict__ y_enc,
                     const float* __restrict__ conv_w, const float* __restrict__ conv_b,
                     const float* __restrict__ bn_w, const float* __restrict__ bn_b,
                     _Float16* __restrict__ feat)
{
    const int t = blockIdx.x;
    const float w0=conv_w[0], w1=conv_w[1], w2=conv_w[2], cb=conv_b[0];
    const float* src = (t < 96) ? (x_enc + (size_t)t*21) : (y_enc + (size_t)(t-96)*21);

    float xv[4][FRAW];
    float s=0.f, ss=0.f;
    #pragma unroll
    for (int rr=0; rr<4; ++rr){
        const int row = threadIdx.x + 1024*rr;
        const float* xr = src + (size_t)row*2016;    // 96*21
        #pragma unroll
        for (int f=0; f<FRAW; ++f) xv[rr][f] = xr[f];
        #pragma unroll
        for (int i=0; i<FCONV; ++i){
            float y = fmaf(w0, xv[rr][(i+18)%20], fmaf(w1, xv[rr][(i+19)%20], fmaf(w2, xv[rr][i%20], cb)));
            s += y; ss = fmaf(y, y, ss);
        }
    }
    #pragma unroll
    for (int o=32; o>0; o>>=1){ s += __shfl_down(s,o); ss += __shfl_down(ss,o); }
    __shared__ float rs[16], rq[16], ab[2];
    const int wid = threadIdx.x >> 6, lid = threadIdx.x & 63;
    if (lid == 0){ rs[wid]=s; rq[wid]=ss; }
    __syncthreads();
    if (threadIdx.x == 0){
        float S=0.f, Q=0.f;
        #pragma unroll
        for (int i=0;i<16;++i){ S+=rs[i]; Q+=rq[i]; }
        const float N = (float)BATCH*(float)FCONV;
        float mu  = S/N;
        float var = Q/N - mu*mu;
        float A   = rsqrtf(var + 1e-5f) * bn_w[0];
        ab[0]=A; ab[1]=bn_b[0] - mu*A;
    }
    __syncthreads();
    const float A = ab[0], Bc = ab[1];

    #pragma unroll
    for (int rr=0; rr<4; ++rr){
        const int row = threadIdx.x + 1024*rr;
        float yv[FCONV];
        #pragma unroll
        for (int i=0; i<FCONV; ++i){
            float y = fmaf(w0, xv[rr][(i+18)%20], fmaf(w1, xv[rr][(i+19)%20], fmaf(w2, xv[rr][i%20], cb)));
            y = fmaf(y, A, Bc);
            yv[i] = (y > 0.f) ? y : (__expf(y) - 1.f);   // ELU
        }
        _Float16* fo = feat + ((size_t)t*BATCH + row)*FCNN;
        #pragma unroll
        for (int i=0; i<FCNN; ++i){
            float m = (i==0) ? fmaxf(yv[0], yv[1])
                             : fmaxf(yv[2*i-1], fmaxf(yv[2*i], yv[2*i+1]));
            fo[i] = (_Float16)m;
        }
    }
}

// -------- kernel 2: unified-buffer pipelined MFMA LSTM, SIMD-balanced -------
// Same dataflow/races/numerics as R14/R15; ONLY the wave->work map changes.
// Waves map to SIMDs as wv%4; per SIMD: {2-tile, 2-tile, 1-tile, head|feat}
// = exactly 5 gate tiles/SIMD (was 6 on SIMD0/1 in R14/R15 -> convoy pace).
//   wv0-3 : L0 2-tile (tiles 0-7)    wv4-7 : L1 2-tile (tiles 0-7)
//   wv8-9 : L0 1-tile (tiles 8,9)    wv10-11: L1 1-tile (tiles 8,9)
//   wv12-13: heads                   wv14-15: feat staging
// V (mod-3), K=96, fp16: k 0..10 feat | 11..50 h0 | 51..55 ZERO | 56..95 h1.
// W hi/lo split in registers (REQUIRED per R13 failure); x/h fp16 (proven).
__global__ __launch_bounds__(NTH, 4)
void lstm_kernel(const _Float16* __restrict__ feat,
                 const float* __restrict__ w_ih0, const float* __restrict__ w_hh0, const float* __restrict__ b0,
                 const float* __restrict__ w_ih1, const float* __restrict__ w_hh1, const float* __restrict__ b1,
                 const float* __restrict__ w_gamma, const float* __restrict__ b_gamma,
                 const float* __restrict__ w_eta,   const float* __restrict__ b_eta,
                 float* __restrict__ out)
{
    __shared__ __align__(16) _Float16 V[3*1536];

    const int tid  = threadIdx.x;
    const int l    = tid & 63;
    const int wv   = tid >> 6;
    const int q    = l >> 4;
    const int mr   = l & 15;
    const int row0 = blockIdx.x * ROWSPB;

    // role decomposition (wave-uniform): per-SIMD balanced
    int role, t0, ntl;
    if      (wv < 4){  role=0; t0=2*wv;       ntl=2; }   // L0 tiles 0-7
    else if (wv < 8){  role=1; t0=2*(wv-4);   ntl=2; }   // L1 tiles 0-7
    else if (wv < 10){ role=0; t0=8+(wv-8);   ntl=1; }   // L0 tiles 8,9
    else if (wv < 12){ role=1; t0=8+(wv-10);  ntl=1; }   // L1 tiles 8,9
    else if (wv < 14){ role=2; t0=0;          ntl=0; }   // heads
    else            {  role=3; t0=0;          ntl=0; }   // feat staging
    const bool isL0 = (role==0), isL1 = (role==1);
    const bool two  = (ntl==2);

    // ---- zero LDS (k51-55 / k91-95 pads must stay zero forever) ----
    { uint32_t* z=(uint32_t*)V; for(int i=tid;i<2304;i+=NTH) z[i]=0u; }

    // =================== per-role setup ===================
    half8 a0h[2][2], a0l[2][2];
    half8 a1h[2][3], a1l[2][3];
    half8 ahd[3];
    f32x4 bias0[2]={{0,0,0,0},{0,0,0,0}}, bias1[2]={{0,0,0,0},{0,0,0,0}};
    f32x4 biash={0,0,0,0};
    int woH0[2]={0,0}, woH1[2]={0,0};
    int fW0=0, fW1=0; bool fV0=false, fV1=false;
    const _Float16* fG0 = feat; const _Float16* fG1 = feat;

    if (isL0){
        #pragma unroll
        for (int g=0; g<2; ++g){
            if (g < ntl){
                const int T  = t0 + g;
                const int uA = 4*T + (mr >> 2);
                const int RA = (mr & 3)*40 + uA;       // torch row: gate-major
                #pragma unroll
                for (int cc=0; cc<2; ++cc){
                    #pragma unroll
                    for (int ii=0; ii<8; ++ii){
                        int k = 32*cc + 8*q + ii;
                        float v = (k<11) ? w_ih0[RA*11+k] : ((k<51) ? w_hh0[RA*40+k-11] : 0.f);
                        _Float16 h = (_Float16)v;
                        a0h[g][cc][ii]=h; a0l[g][cc][ii]=(_Float16)(v-(float)h);
                    }
                }
                const int u = 4*T + q;
                bias0[g][0]=b0[u]; bias0[g][1]=b0[40+u]; bias0[g][2]=b0[80+u]; bias0[g][3]=b0[120+u];
                woH0[g] = offk(11+u, mr);
            }
        }
    } else if (isL1){
        #pragma unroll
        for (int g=0; g<2; ++g){
            if (g < ntl){
                const int T  = t0 + g;
                const int uA = 4*T + (mr >> 2);
                const int RA = (mr & 3)*40 + uA;
                #pragma unroll
                for (int cc=0; cc<3; ++cc){
                    #pragma unroll
                    for (int ii=0; ii<8; ++ii){
                        int k = 32*cc + 8*q + ii;
                        float v = 0.f;
                        if (k>=11 && k<51)      v = w_ih1[RA*40 + (k-11)];
                        else if (k>=56)         v = w_hh1[RA*40 + (k-56)];
                        _Float16 h = (_Float16)v;
                        a1h[g][cc][ii]=h; a1l[g][cc][ii]=(_Float16)(v-(float)h);
                    }
                }
                const int u = 4*T + q;
                bias1[g][0]=b1[u]; bias1[g][1]=b1[40+u]; bias1[g][2]=b1[80+u]; bias1[g][3]=b1[120+u];
                woH1[g] = offk(56+u, mr);
            }
        }
    } else if (role == 2){
        const int hw = wv - 12;
        const int jo = 16*hw + mr;
        #pragma unroll
        for (int cc=0; cc<3; ++cc){
            #pragma unroll
            for (int ii=0; ii<8; ++ii){
                int k = 32*cc + 8*q + ii;
                float v = 0.f;
                if (jo < NOUT){
                    if (k>=11 && k<51) v = (jo==0) ? w_gamma[2*(k-11)]   : w_eta[(jo-1)*80 + 2*(k-11)];
                    else if (k>=56)    v = (jo==0) ? w_gamma[2*(k-56)+1] : w_eta[(jo-1)*80 + 2*(k-56)+1];
                }
                ahd[cc][ii] = (_Float16)v;
            }
        }
        #pragma unroll
        for (int e=0; e<4; ++e){
            int j2 = 16*hw + 4*q + e;
            biash[e] = (j2 < NOUT) ? ((j2==0) ? b_gamma[0] : b_eta[j2-1]) : 0.f;
        }
    } else {
        const int hl = tid - 896;                      // wv14-15 -> 0..127
        int i0 = hl, i1 = hl + 128;
        fV0 = (i0 < ROWSPB*FCNN); fV1 = (i1 < ROWSPB*FCNN);
        { int r = i0/FCNN, f = i0 - FCNN*r; r &= 15; fW0 = offk(f, r);
          fG0 = feat + (size_t)(row0 + r)*FCNN + f; }
        { int ix = fV1 ? i1 : 0;
          int r = ix/FCNN, f = ix - FCNN*(ix/FCNN); r &= 15; fW1 = offk(f, r);
          fG1 = feat + (size_t)(row0 + r)*FCNN + f; }
    }

    __syncthreads();    // zero-init visible before feat(0) staging
    _Float16 fA0=(_Float16)0.f, fA1=(_Float16)0.f, fB0=(_Float16)0.f, fB1=(_Float16)0.f;
    if (role == 3){
        if (fV0) V[fW0] = fG0[0];                      // feat(0) -> V[0]
        if (fV1) V[fW1] = fG1[0];
        const size_t fs = (size_t)BATCH*FCNN;          // preload feat(1)
        if (fV0) fB0 = fG0[fs];
        if (fV1) fB1 = fG1[fs];
    }
    __syncthreads();

    float c0[2]={0.f,0.f}, c1[2]={0.f,0.f};
    const size_t featStep = (size_t)BATCH*FCNN;
    const _Float16* Vr = V + l*8;                      // hoisted read base

    if (isL0){
        _Float16* wpa = V + woH0[0];
        _Float16* wpb = V + woH0[1];
        #define L0T(G,WP,C,CN) do{ \
            f32x4 acc = bias0[G]; \
            acc = MFMA16(a0h[G][0], x0, acc); \
            acc = MFMA16(a0l[G][0], x0, acc); \
            acc = MFMA16(a0h[G][1], x1, acc); \
            acc = MFMA16(a0l[G][1], x1, acc); \
            float ig=sigm_(acc[0]), fg=sigm_(acc[1]), gv=tanh_(acc[2]), og=sigm_(acc[3]); \
            c0[G] = fmaf(fg, c0[G], ig*gv); \
            WP[(CN)*1536] = (_Float16)(og * tanh_(c0[G])); \
        }while(0)
        #define L0B(C,CN) do{ \
            half8 x0 = *(const half8*)(Vr + (C)*1536); \
            half8 x1 = *(const half8*)(Vr + (C)*1536 + 512); \
            L0T(0,wpa,C,CN); \
            if (two) L0T(1,wpb,C,CN); \
        }while(0)
        L0B(0,1); WGBAR();      // i = 0
        L0B(1,2); WGBAR();      // i = 1
        for (int m=0; m<32; ++m){
            #pragma unroll
            for (int k=0; k<6; ++k){
                const int i = 2 + 6*m + k;
                if (i < TSTEPS) L0B((k+2)%3, k%3);
                WGBAR();
            }
        }
        #undef L0B
        #undef L0T
    } else if (isL1){
        _Float16* wpa = V + woH1[0];
        _Float16* wpb = V + woH1[1];
        #define L1T(G,WP,C,CN) do{ \
            f32x4 cA = bias1[G]; \
            cA = MFMA16(a1h[G][0], y0, cA); cA = MFMA16(a1l[G][0], y0, cA); \
            cA = MFMA16(a1h[G][1], y1, cA); cA = MFMA16(a1l[G][1], y1, cA); \
            f32x4 cB = {0.f,0.f,0.f,0.f}; \
            cB = MFMA16(a1h[G][2], y2, cB); cB = MFMA16(a1l[G][2], y2, cB); \
            f32x4 acc = cA + cB; \
            float ig=sigm_(acc[0]), fg=sigm_(acc[1]), gv=tanh_(acc[2]), og=sigm_(acc[3]); \
            c1[G] = fmaf(fg, c1[G], ig*gv); \
            WP[(CN)*1536] = (_Float16)(og * tanh_(c1[G])); \
        }while(0)
        #define L1B(C,CN) do{ \
            half8 y0 = *(const half8*)(Vr + (C)*1536); \
            half8 y1 = *(const half8*)(Vr + (C)*1536 + 512); \
            half8 y2 = *(const half8*)(Vr + (C)*1536 + 1024); \
            L1T(0,wpa,C,CN); \
            if (two) L1T(1,wpb,C,CN); \
        }while(0)
        WGBAR();                // i = 0 (L1 idle)
        L1B(1,2); WGBAR();      // i = 1
        for (int m=0; m<32; ++m){
            #pragma unroll
            for (int k=0; k<6; ++k){
                const int i = 2 + 6*m + k;
                if (i <= TSTEPS) L1B((k+2)%3, k%3);
                WGBAR();
            }
        }
        #undef L1B
        #undef L1T
    } else if (role == 2){
        const int hw  = wv - 12;
        const int jb  = 16*hw + 4*q;
        float* outB = out + (size_t)(row0 + mr)*NOUT + jb;
        #define HOUT(C,CP,I) do{ \
            half8 z0 = *(const half8*)(Vr + (CP)*1536); \
            half8 z1 = *(const half8*)(Vr + ((q<3)?(CP):(C))*1536 + 512); \
            half8 z2 = *(const half8*)(Vr + (C)*1536 + 1024); \
            f32x4 H = biash; \
            H = MFMA16(ahd[0], z0, H); \
            H = MFMA16(ahd[1], z1, H); \
            H = MFMA16(ahd[2], z2, H); \
            float* op = outB + (size_t)((I)-2)*(BATCH*NOUT); \
            if (hw==0 || q==0){ \
                op[0]=softplus_(H[0]); op[1]=softplus_(H[1]); \
                op[2]=softplus_(H[2]); op[3]=softplus_(H[3]); \
            } else if (q==1){ \
                op[0]=softplus_(H[0]); \
            } \
        }while(0)
        WGBAR();                // i = 0 (heads idle)
        WGBAR();                // i = 1 (heads idle)
        for (int m=0; m<32; ++m){
            #pragma unroll
            for (int k=0; k<6; ++k){
                const int i = 2 + 6*m + k;
                HOUT((k+2)%3, (k+1)%3, i);
                WGBAR();
            }
        }
        #undef HOUT
    } else {
        _Float16* fp0 = V + fW0;
        _Float16* fp1 = V + fW1;
        #define HFEAT(CN,PAR,I) do{ \
            if ((I) < TSTEPS-1){ \
                _Float16 v0 = (PAR) ? fA0 : fB0; \
                _Float16 v1 = (PAR) ? fA1 : fB1; \
                if (fV0) fp0[(CN)*1536] = v0; \
                if (fV1) fp1[(CN)*1536] = v1; \
            } \
            if ((I)+2 < TSTEPS){ \
                size_t o = (size_t)((I)+2)*featStep; \
                if (PAR){ if(fV0) fB0=fG0[o]; if(fV1) fB1=fG1[o]; } \
                else    { if(fV0) fA0=fG0[o]; if(fV1) fA1=fG1[o]; } \
            } \
        }while(0)
        HFEAT(1,0,0); WGBAR();      // i = 0
        HFEAT(2,1,1); WGBAR();      // i = 1
        for (int m=0; m<32; ++m){
            #pragma unroll
            for (int k=0; k<6; ++k){
                const int i = 2 + 6*m + k;
                HFEAT(k%3, k%2, i);
                WGBAR();
            }
        }
        #undef HFEAT
    }
}

// ---------------------------------------------------------------------------
extern "C" void kernel_launch(void* const* d_in, const int* in_sizes, int n_in,
                              void* d_out, int out_size, void* d_ws, size_t ws_size,
                              hipStream_t stream)
{
    (void)in_sizes; (void)n_in; (void)out_size; (void)ws_size;
    const float* x_enc   = (const float*)d_in[0];
    const float* y_enc   = (const float*)d_in[3];
    const float* conv_w  = (const float*)d_in[5];
    const float* conv_b  = (const float*)d_in[6];
    const float* bn_w    = (const float*)d_in[7];
    const float* bn_b    = (const float*)d_in[8];
    const float* w_ih0   = (const float*)d_in[9];
    const float* w_hh0   = (const float*)d_in[10];
    const float* b0      = (const float*)d_in[11];
    const float* w_ih1   = (const float*)d_in[12];
    const float* w_hh1   = (const float*)d_in[13];
    const float* b1      = (const float*)d_in[14];
    const float* w_gamma = (const float*)d_in[15];
    const float* b_gamma = (const float*)d_in[16];
    const float* w_eta   = (const float*)d_in[17];
    const float* b_eta   = (const float*)d_in[18];

    float*     out   = (float*)d_out;
    _Float16*  feat  = (_Float16*)((char*)d_ws + FEAT_OFF);

    statfeat_kernel<<<TSTEPS, 1024, 0, stream>>>(x_enc, y_enc, conv_w, conv_b, bn_w, bn_b, feat);
    lstm_kernel<<<NBLK, NTH, 0, stream>>>(feat,
        w_ih0, w_hh0, b0, w_ih1, w_hh1, b1, w_gamma, b_gamma, w_eta, b_eta, out);
}